// Round 7
// baseline (150.530 us; speedup 1.0000x reference)
//
#include <hip/hip_runtime.h>
#include <stdint.h>

#define BATCH    512
#define NPIX     16384             // H*W = 128*128
#define NTHREADS 1024
#define PPT      (NPIX / NTHREADS) // 16 pixels per thread
#define TSLOTS   8192              // 32-bit key slots, reused over 4 passes
#define TMASK    (TSLOTS - 1)
#define EMPTYK   0xFFFFFFFFu       // max real key is 0xFEFEFEFE (channels <= 254)
#define MAXDUP   256

__global__ __launch_bounds__(NTHREADS, 1)
void palette_kernel(const float* __restrict__ in,
                    float* __restrict__ out_pal,
                    float* __restrict__ out_cnt) {
    __shared__ uint32_t table[TSLOTS];     // 32 KiB exact-key table (per pass)
    __shared__ uint32_t dupkeys[MAXDUP];   // true duplicate keys
    __shared__ uint32_t nonfirst[MAXDUP];  // pixel positions that are not first
    __shared__ uint32_t s_ndup, s_nnf, s_minidx;

    const int img = blockIdx.x;
    const int tid = threadIdx.x;
    const float4* src = (const float4*)(in + (size_t)img * NPIX * 4);
    float4* dst = (float4*)(out_pal + (size_t)img * NPIX * 4);

    if (tid == 0) { s_ndup = 0; s_nnf = 0; }

    // ---- load + quantize (matches jnp: (x+1)*127.5 in f32, trunc toward 0) ----
    uint32_t mykeys[PPT];
#pragma unroll
    for (int j = 0; j < PPT; ++j) {
        int p = j * NTHREADS + tid;
        float4 v = src[p];
        uint32_t c0 = (uint32_t)(int)((v.x + 1.0f) * 127.5f);
        uint32_t c1 = (uint32_t)(int)((v.y + 1.0f) * 127.5f);
        uint32_t c2 = (uint32_t)(int)((v.z + 1.0f) * 127.5f);
        uint32_t c3 = (uint32_t)(int)((v.w + 1.0f) * 127.5f);
        mykeys[j] = (c0 << 24) | (c1 << 16) | (c2 << 8) | c3;
    }

    // ---- exact duplicate detection: 4 passes over key classes (key>>30),
    //      each pass inserts ~4096 keys into the 8192-slot table (load 0.5).
    //      Single-CAS probe per slot, R4-proven cheap. Candidates are TRUE
    //      duplicates (exact 32-bit keys, no fingerprint ambiguity).
    for (uint32_t pass = 0; pass < 4; ++pass) {
        if (pass) __syncthreads();        // prior pass's probes done
        {   // clear table: 2048 uint4 = 8192 words
            uint4* t4 = (uint4*)table;
            uint4 e = make_uint4(EMPTYK, EMPTYK, EMPTYK, EMPTYK);
            t4[tid] = e;
            t4[tid + NTHREADS] = e;
        }
        __syncthreads();
#pragma unroll
        for (int j = 0; j < PPT; ++j) {
            uint32_t key = mykeys[j];
            if ((key >> 30) != pass) continue;
            uint32_t h = (key * 2654435761u) >> 19;  // 13-bit start slot
            while (true) {
                uint32_t old = atomicCAS(&table[h & TMASK], EMPTYK, key);
                if (old == EMPTYK) break;            // inserted
                if (old == key) {                    // true duplicate occurrence
                    uint32_t s = atomicAdd(&s_ndup, 1u);
                    if (s < MAXDUP) dupkeys[s] = key;
                    break;
                }
                ++h;
            }
        }
    }
    __syncthreads();

    // ---- resolve duplicates canonically (min pixel index is first) ----
    uint32_t nd = s_ndup; if (nd > MAXDUP) nd = MAXDUP;
    for (uint32_t e = 0; e < nd; ++e) {
        uint32_t dkey = dupkeys[e];
        bool seen = false;                 // skip repeated list entries (uniform)
        for (uint32_t e2 = 0; e2 < e; ++e2) seen |= (dupkeys[e2] == dkey);
        if (seen) continue;
        if (tid == 0) s_minidx = 0xFFFFFFFFu;
        __syncthreads();
#pragma unroll
        for (int j = 0; j < PPT; ++j)
            if (mykeys[j] == dkey) atomicMin(&s_minidx, (uint32_t)(j * NTHREADS + tid));
        __syncthreads();
        uint32_t mi = s_minidx;
#pragma unroll
        for (int j = 0; j < PPT; ++j) {
            uint32_t p = (uint32_t)(j * NTHREADS + tid);
            if (mykeys[j] == dkey && p != mi) {
                uint32_t s = atomicAdd(&s_nnf, 1u);
                if (s < MAXDUP) nonfirst[s] = p;
            }
        }
        __syncthreads();
    }

    uint32_t nnf = s_nnf; if (nnf > MAXDUP) nnf = MAXDUP;
    uint32_t count = NPIX - nnf;

    // ---- write palette rows: rank(p) = p - |{q in nonfirst : q < p}| ----
#pragma unroll
    for (int j = 0; j < PPT; ++j) {
        uint32_t p = (uint32_t)(j * NTHREADS + tid);
        uint32_t skip = 0;
        bool isnf = false;
        for (uint32_t k = 0; k < nnf; ++k) {   // nnf == 0 almost always
            uint32_t q = nonfirst[k];
            skip += (q < p) ? 1u : 0u;
            isnf |= (q == p);
        }
        if (!isnf) {
            uint32_t key = mykeys[j];
            float4 o;
            o.x = (float)((key >> 24) & 255u) / 127.5f - 1.0f;
            o.y = (float)((key >> 16) & 255u) / 127.5f - 1.0f;
            o.z = (float)((key >> 8)  & 255u) / 127.5f - 1.0f;
            o.w = (float)( key        & 255u) / 127.5f - 1.0f;
            dst[p - skip] = o;
        }
    }
    // ---- zero the padded tail rows (nnf rows, usually none) ----
    float4 z = make_float4(0.f, 0.f, 0.f, 0.f);
    for (uint32_t r = count + tid; r < NPIX; r += NTHREADS) dst[r] = z;
    // ---- count (written as float; whole d_out is read back as f32) ----
    if (tid == 0) out_cnt[img] = (float)count;
}

extern "C" void kernel_launch(void* const* d_in, const int* in_sizes, int n_in,
                              void* d_out, int out_size, void* d_ws, size_t ws_size,
                              hipStream_t stream) {
    const float* in = (const float*)d_in[0];
    float* out = (float*)d_out;
    float* cnt = out + (size_t)BATCH * NPIX * 4;
    hipLaunchKernelGGL(palette_kernel, dim3(BATCH), dim3(NTHREADS), 0, stream,
                       in, out, cnt);
}

// Round 8
// 130.633 us; speedup vs baseline: 1.1523x; 1.1523x over previous
//
#include <hip/hip_runtime.h>
#include <stdint.h>

#define BATCH    512
#define NPIX     16384             // H*W = 128*128
#define NTHREADS 512               // 8 waves: small enough to pack 3-4 blocks/CU
#define PPT      (NPIX / NTHREADS) // 32 pixels per thread
#define TSLOTS   8192              // 32-bit key slots, reused over 4 passes
#define TMASK    (TSLOTS - 1)
#define EMPTYK   0xFFFFFFFFu       // max real key is 0xFEFEFEFE (channels <= 254)
#define MAXDUP   256

__global__ __launch_bounds__(NTHREADS, 4)  // gentle VGPR cap (~128), no spill risk
void palette_kernel(const float* __restrict__ in,
                    float* __restrict__ out_pal,
                    float* __restrict__ out_cnt) {
    __shared__ uint32_t table[TSLOTS];     // 32 KiB exact-key table (per pass)
    __shared__ uint32_t dupkeys[MAXDUP];   // true duplicate keys
    __shared__ uint32_t nonfirst[MAXDUP];  // pixel positions that are not first
    __shared__ uint32_t s_ndup, s_nnf, s_minidx;

    const int img = blockIdx.x;
    const int tid = threadIdx.x;
    const float4* src = (const float4*)(in + (size_t)img * NPIX * 4);
    float4* dst = (float4*)(out_pal + (size_t)img * NPIX * 4);

    if (tid == 0) { s_ndup = 0; s_nnf = 0; }

    // ---- load + quantize (matches jnp: (x+1)*127.5 in f32, trunc toward 0) ----
    uint32_t mykeys[PPT];
#pragma unroll
    for (int j = 0; j < PPT; ++j) {
        int p = j * NTHREADS + tid;
        float4 v = src[p];
        uint32_t c0 = (uint32_t)(int)((v.x + 1.0f) * 127.5f);
        uint32_t c1 = (uint32_t)(int)((v.y + 1.0f) * 127.5f);
        uint32_t c2 = (uint32_t)(int)((v.z + 1.0f) * 127.5f);
        uint32_t c3 = (uint32_t)(int)((v.w + 1.0f) * 127.5f);
        mykeys[j] = (c0 << 24) | (c1 << 16) | (c2 << 8) | c3;
    }

    // ---- exact duplicate detection: 4 passes over key classes (key>>30),
    //      each pass inserts ~4096 keys into the 8192-slot table (load 0.5).
    //      Single-CAS probe per slot; candidates are TRUE duplicates.
    for (uint32_t pass = 0; pass < 4; ++pass) {
        if (pass) __syncthreads();        // prior pass's probes done
        {   // clear table: 2048 uint4 = 8192 words
            uint4* t4 = (uint4*)table;
            uint4 e = make_uint4(EMPTYK, EMPTYK, EMPTYK, EMPTYK);
#pragma unroll
            for (int i = 0; i < TSLOTS / 4 / NTHREADS; ++i)
                t4[i * NTHREADS + tid] = e;
        }
        __syncthreads();
#pragma unroll
        for (int j = 0; j < PPT; ++j) {
            uint32_t key = mykeys[j];
            if ((key >> 30) != pass) continue;
            uint32_t h = (key * 2654435761u) >> 19;  // 13-bit start slot
            while (true) {
                uint32_t old = atomicCAS(&table[h & TMASK], EMPTYK, key);
                if (old == EMPTYK) break;            // inserted
                if (old == key) {                    // true duplicate occurrence
                    uint32_t s = atomicAdd(&s_ndup, 1u);
                    if (s < MAXDUP) dupkeys[s] = key;
                    break;
                }
                ++h;
            }
        }
    }
    __syncthreads();

    // ---- resolve duplicates canonically (min pixel index is first) ----
    uint32_t nd = s_ndup; if (nd > MAXDUP) nd = MAXDUP;
    for (uint32_t e = 0; e < nd; ++e) {
        uint32_t dkey = dupkeys[e];
        bool seen = false;                 // skip repeated list entries (uniform)
        for (uint32_t e2 = 0; e2 < e; ++e2) seen |= (dupkeys[e2] == dkey);
        if (seen) continue;
        if (tid == 0) s_minidx = 0xFFFFFFFFu;
        __syncthreads();
#pragma unroll
        for (int j = 0; j < PPT; ++j)
            if (mykeys[j] == dkey) atomicMin(&s_minidx, (uint32_t)(j * NTHREADS + tid));
        __syncthreads();
        uint32_t mi = s_minidx;
#pragma unroll
        for (int j = 0; j < PPT; ++j) {
            uint32_t p = (uint32_t)(j * NTHREADS + tid);
            if (mykeys[j] == dkey && p != mi) {
                uint32_t s = atomicAdd(&s_nnf, 1u);
                if (s < MAXDUP) nonfirst[s] = p;
            }
        }
        __syncthreads();
    }

    uint32_t nnf = s_nnf; if (nnf > MAXDUP) nnf = MAXDUP;
    uint32_t count = NPIX - nnf;

    // ---- write palette rows: rank(p) = p - |{q in nonfirst : q < p}| ----
#pragma unroll
    for (int j = 0; j < PPT; ++j) {
        uint32_t p = (uint32_t)(j * NTHREADS + tid);
        uint32_t skip = 0;
        bool isnf = false;
        for (uint32_t k = 0; k < nnf; ++k) {   // nnf == 0 almost always
            uint32_t q = nonfirst[k];
            skip += (q < p) ? 1u : 0u;
            isnf |= (q == p);
        }
        if (!isnf) {
            uint32_t key = mykeys[j];
            float4 o;
            o.x = (float)((key >> 24) & 255u) / 127.5f - 1.0f;
            o.y = (float)((key >> 16) & 255u) / 127.5f - 1.0f;
            o.z = (float)((key >> 8)  & 255u) / 127.5f - 1.0f;
            o.w = (float)( key        & 255u) / 127.5f - 1.0f;
            dst[p - skip] = o;
        }
    }
    // ---- zero the padded tail rows (nnf rows, usually none) ----
    float4 z = make_float4(0.f, 0.f, 0.f, 0.f);
    for (uint32_t r = count + tid; r < NPIX; r += NTHREADS) dst[r] = z;
    // ---- count (written as float; whole d_out is read back as f32) ----
    if (tid == 0) out_cnt[img] = (float)count;
}

extern "C" void kernel_launch(void* const* d_in, const int* in_sizes, int n_in,
                              void* d_out, int out_size, void* d_ws, size_t ws_size,
                              hipStream_t stream) {
    const float* in = (const float*)d_in[0];
    float* out = (float*)d_out;
    float* cnt = out + (size_t)BATCH * NPIX * 4;
    hipLaunchKernelGGL(palette_kernel, dim3(BATCH), dim3(NTHREADS), 0, stream,
                       in, out, cnt);
}

// Round 9
// 101.264 us; speedup vs baseline: 1.4865x; 1.2900x over previous
//
#include <hip/hip_runtime.h>
#include <stdint.h>

#define BATCH    512
#define NPIX     16384             // H*W = 128*128
#define NTHREADS 1024
#define PPT      (NPIX / NTHREADS) // 16 pixels per thread per image
#define TSLOTS   32768             // exact 32-bit key slots, load factor 0.5
#define TMASK    (TSLOTS - 1)
#define EMPTYK   0xFFFFFFFFu       // max real key is 0xFEFEFEFE (channels <= 254)
#define MAXDUP   256
#define IPB      2                 // images per block (grid = BATCH/IPB = 256 = #CUs)

__global__ __launch_bounds__(NTHREADS, 4)   // 16 waves/CU needs VGPR<=128
void palette_kernel(const float* __restrict__ in,
                    float* __restrict__ out_pal,
                    float* __restrict__ out_cnt) {
    __shared__ uint32_t table[TSLOTS];     // 128 KiB exact-key table
    __shared__ uint32_t dupkeys[MAXDUP];   // true duplicate keys
    __shared__ uint32_t nonfirst[MAXDUP];  // pixel positions that are not first
    __shared__ uint32_t s_ndup, s_nnf, s_minidx;

    const int tid = threadIdx.x;

    // ---- prologue: issue image 0's loads ----
    float4 vcur[PPT];
    {
        const float4* src = (const float4*)(in + (size_t)(IPB * blockIdx.x) * NPIX * 4);
#pragma unroll
        for (int j = 0; j < PPT; ++j) vcur[j] = src[j * NTHREADS + tid];
    }

#pragma unroll
    for (int s = 0; s < IPB; ++s) {
        const int img = IPB * blockIdx.x + s;
        float4* dst = (float4*)(out_pal + (size_t)img * NPIX * 4);

        // ---- quantize current image (matches jnp: (x+1)*127.5 f32, trunc) ----
        uint32_t k[PPT];
#pragma unroll
        for (int j = 0; j < PPT; ++j) {
            float4 v = vcur[j];
            uint32_t c0 = (uint32_t)(int)((v.x + 1.0f) * 127.5f);
            uint32_t c1 = (uint32_t)(int)((v.y + 1.0f) * 127.5f);
            uint32_t c2 = (uint32_t)(int)((v.z + 1.0f) * 127.5f);
            uint32_t c3 = (uint32_t)(int)((v.w + 1.0f) * 127.5f);
            k[j] = (c0 << 24) | (c1 << 16) | (c2 << 8) | c3;
        }

        // ---- prefetch next image NOW: its load latency/BW hides under this
        //      image's clear+insert+resolve+write phases ----
        if (s + 1 < IPB) {
            const float4* nsrc = (const float4*)(in + (size_t)(img + 1) * NPIX * 4);
#pragma unroll
            for (int j = 0; j < PPT; ++j) vcur[j] = nsrc[j * NTHREADS + tid];
        }

        __syncthreads();   // previous iteration's readers of table/lists are done
        // ---- clear table + per-image counters ----
        {
            uint4* t4 = (uint4*)table;
            uint4 e = make_uint4(EMPTYK, EMPTYK, EMPTYK, EMPTYK);
#pragma unroll
            for (int i = 0; i < TSLOTS / 4 / NTHREADS; ++i) t4[i * NTHREADS + tid] = e;
        }
        if (tid == 0) { s_ndup = 0; s_nnf = 0; }
        __syncthreads();

        // ---- exact duplicate detection via single-CAS linear probing ----
#pragma unroll
        for (int j = 0; j < PPT; ++j) {
            uint32_t key = k[j];
            uint32_t h = (key * 2654435761u) >> 17;  // 15-bit start slot
            while (true) {
                uint32_t old = atomicCAS(&table[h & TMASK], EMPTYK, key);
                if (old == EMPTYK) break;            // inserted
                if (old == key) {                    // true duplicate occurrence
                    uint32_t sl = atomicAdd(&s_ndup, 1u);
                    if (sl < MAXDUP) dupkeys[sl] = key;
                    break;
                }
                ++h;
            }
        }
        __syncthreads();

        // ---- resolve duplicates canonically (min pixel index is first) ----
        uint32_t nd = s_ndup; if (nd > MAXDUP) nd = MAXDUP;
        for (uint32_t e = 0; e < nd; ++e) {
            uint32_t dkey = dupkeys[e];
            bool seen = false;                       // skip repeated entries (uniform)
            for (uint32_t e2 = 0; e2 < e; ++e2) seen |= (dupkeys[e2] == dkey);
            if (seen) continue;
            if (tid == 0) s_minidx = 0xFFFFFFFFu;
            __syncthreads();
#pragma unroll
            for (int j = 0; j < PPT; ++j)
                if (k[j] == dkey) atomicMin(&s_minidx, (uint32_t)(j * NTHREADS + tid));
            __syncthreads();
            uint32_t mi = s_minidx;
#pragma unroll
            for (int j = 0; j < PPT; ++j) {
                uint32_t p = (uint32_t)(j * NTHREADS + tid);
                if (k[j] == dkey && p != mi) {
                    uint32_t sl = atomicAdd(&s_nnf, 1u);
                    if (sl < MAXDUP) nonfirst[sl] = p;
                }
            }
            __syncthreads();
        }
        __syncthreads();   // s_nnf / nonfirst final before the write phase reads them

        uint32_t nnf = s_nnf; if (nnf > MAXDUP) nnf = MAXDUP;
        uint32_t count = NPIX - nnf;

        // ---- write palette rows: rank(p) = p - |{q in nonfirst : q < p}| ----
#pragma unroll
        for (int j = 0; j < PPT; ++j) {
            uint32_t p = (uint32_t)(j * NTHREADS + tid);
            uint32_t skip = 0;
            bool isnf = false;
            for (uint32_t kk = 0; kk < nnf; ++kk) {  // nnf == 0 almost always
                uint32_t q = nonfirst[kk];
                skip += (q < p) ? 1u : 0u;
                isnf |= (q == p);
            }
            if (!isnf) {
                uint32_t key = k[j];
                float4 o;
                o.x = (float)((key >> 24) & 255u) / 127.5f - 1.0f;
                o.y = (float)((key >> 16) & 255u) / 127.5f - 1.0f;
                o.z = (float)((key >> 8)  & 255u) / 127.5f - 1.0f;
                o.w = (float)( key        & 255u) / 127.5f - 1.0f;
                dst[p - skip] = o;
            }
        }
        // ---- zero the padded tail rows (nnf rows, usually none) ----
        float4 z = make_float4(0.f, 0.f, 0.f, 0.f);
        for (uint32_t r = count + tid; r < NPIX; r += NTHREADS) dst[r] = z;
        // ---- count (written as float; whole d_out is read back as f32) ----
        if (tid == 0) out_cnt[img] = (float)count;
    }
}

extern "C" void kernel_launch(void* const* d_in, const int* in_sizes, int n_in,
                              void* d_out, int out_size, void* d_ws, size_t ws_size,
                              hipStream_t stream) {
    const float* in = (const float*)d_in[0];
    float* out = (float*)d_out;
    float* cnt = out + (size_t)BATCH * NPIX * 4;
    hipLaunchKernelGGL(palette_kernel, dim3(BATCH / IPB), dim3(NTHREADS), 0, stream,
                       in, out, cnt);
}

// Round 11
// 80.012 us; speedup vs baseline: 1.8813x; 1.2656x over previous
//
#include <hip/hip_runtime.h>
#include <stdint.h>

#define BATCH    512
#define NPIX     16384             // H*W = 128*128
#define NTHREADS 1024
#define PPT      (NPIX / NTHREADS) // 16 pixels per thread per image
#define CHUNK    4                 // float4 loads per thread per pipeline stage
#define NCHUNK   (PPT / CHUNK)
#define TSLOTS   32768             // exact 32-bit key slots, load factor 0.5
#define TMASK    (TSLOTS - 1)
#define EMPTYK   0xFFFFFFFFu       // max real key is 0xFEFEFEFE (channels <= 254)
#define MAXDUP   256
#define IPB      2                 // images per block (grid = 256 = #CUs)

// No __launch_bounds__: R5/R9 showed caps force spills (FETCH/WRITE inflation).
// Natural allocation ~90-120 VGPR <= 128 keeps 16 waves/CU.
__global__ void palette_kernel(const float* __restrict__ in,
                               float* __restrict__ out_pal,
                               float* __restrict__ out_cnt) {
    __shared__ uint32_t table[TSLOTS];     // 128 KiB exact-key table
    __shared__ uint32_t dupkeys[MAXDUP];   // true duplicate keys
    __shared__ uint32_t nonfirst[MAXDUP];  // pixel positions that are not first
    __shared__ uint32_t s_ndup, s_nnf, s_minidx;

    const int tid = threadIdx.x;

    // ---- prologue: issue image 0's chunk-0 loads ----
    float4 v[CHUNK];
    {
        const float4* src = (const float4*)(in + (size_t)(IPB * blockIdx.x) * NPIX * 4);
#pragma unroll
        for (int jj = 0; jj < CHUNK; ++jj) v[jj] = src[jj * NTHREADS + tid];
    }

#pragma unroll
    for (int s = 0; s < IPB; ++s) {
        const int img = IPB * blockIdx.x + s;
        const float4* src = (const float4*)(in + (size_t)img * NPIX * 4);
        float4* dst = (float4*)(out_pal + (size_t)img * NPIX * 4);

        // ---- clear table + counters (overlaps prev image's store drain) ----
        {
            uint4* t4 = (uint4*)table;
            uint4 e = make_uint4(EMPTYK, EMPTYK, EMPTYK, EMPTYK);
#pragma unroll
            for (int i = 0; i < TSLOTS / 4 / NTHREADS; ++i) t4[i * NTHREADS + tid] = e;
        }
        if (tid == 0) { s_ndup = 0; s_nnf = 0; }
        __syncthreads();   // bar1: clear visible; prev writes + chunk0 loads drained

        // ---- chunked load -> quantize -> CAS-insert pipeline (barrier-free) ----
        uint32_t k[PPT];
#pragma unroll
        for (int c = 0; c < NCHUNK; ++c) {
            float4 w[CHUNK];
            if (c + 1 < NCHUNK) {   // issue next chunk's loads FIRST
#pragma unroll
                for (int jj = 0; jj < CHUNK; ++jj)
                    w[jj] = src[(CHUNK * (c + 1) + jj) * NTHREADS + tid];
            }
            // quantize current chunk (matches jnp: (x+1)*127.5 f32, trunc to 0)
#pragma unroll
            for (int jj = 0; jj < CHUNK; ++jj) {
                float4 x = v[jj];
                uint32_t c0 = (uint32_t)(int)((x.x + 1.0f) * 127.5f);
                uint32_t c1 = (uint32_t)(int)((x.y + 1.0f) * 127.5f);
                uint32_t c2 = (uint32_t)(int)((x.z + 1.0f) * 127.5f);
                uint32_t c3 = (uint32_t)(int)((x.w + 1.0f) * 127.5f);
                k[CHUNK * c + jj] = (c0 << 24) | (c1 << 16) | (c2 << 8) | c3;
            }
            // insert current chunk: single-CAS linear probing, order-free
#pragma unroll
            for (int jj = 0; jj < CHUNK; ++jj) {
                uint32_t key = k[CHUNK * c + jj];
                uint32_t h = (key * 2654435761u) >> 17;  // 15-bit start slot
                while (true) {
                    uint32_t old = atomicCAS(&table[h & TMASK], EMPTYK, key);
                    if (old == EMPTYK) break;            // inserted
                    if (old == key) {                    // true duplicate occurrence
                        uint32_t sl = atomicAdd(&s_ndup, 1u);
                        if (sl < MAXDUP) dupkeys[sl] = key;
                        break;
                    }
                    ++h;
                }
            }
            if (c + 1 < NCHUNK) {
#pragma unroll
                for (int jj = 0; jj < CHUNK; ++jj) v[jj] = w[jj];
            }
        }
        __syncthreads();   // bar2: inserts done

        // ---- resolve duplicates canonically (min pixel index is first) ----
        uint32_t nd = s_ndup; if (nd > MAXDUP) nd = MAXDUP;
        for (uint32_t e = 0; e < nd; ++e) {
            uint32_t dkey = dupkeys[e];
            bool seen = false;                 // skip repeated entries (uniform)
            for (uint32_t e2 = 0; e2 < e; ++e2) seen |= (dupkeys[e2] == dkey);
            if (seen) continue;
            if (tid == 0) s_minidx = 0xFFFFFFFFu;
            __syncthreads();
#pragma unroll
            for (int j = 0; j < PPT; ++j)
                if (k[j] == dkey) atomicMin(&s_minidx, (uint32_t)(j * NTHREADS + tid));
            __syncthreads();
            uint32_t mi = s_minidx;
#pragma unroll
            for (int j = 0; j < PPT; ++j) {
                uint32_t p = (uint32_t)(j * NTHREADS + tid);
                if (k[j] == dkey && p != mi) {
                    uint32_t sl = atomicAdd(&s_nnf, 1u);
                    if (sl < MAXDUP) nonfirst[sl] = p;
                }
            }
            __syncthreads();
        }
        __syncthreads();   // bar3: s_nnf final
        uint32_t nnf = s_nnf; if (nnf > MAXDUP) nnf = MAXDUP;
        uint32_t count = NPIX - nnf;
        __syncthreads();   // bar4: snapshots taken before next iter's counter reset

        // ---- prefetch next image's chunk 0 (in flight under the store loop) ----
        if (s + 1 < IPB) {
            const float4* nsrc = (const float4*)(in + (size_t)(img + 1) * NPIX * 4);
#pragma unroll
            for (int jj = 0; jj < CHUNK; ++jj) v[jj] = nsrc[jj * NTHREADS + tid];
        }

        // ---- write palette rows: rank(p) = p - |{q in nonfirst : q < p}| ----
#pragma unroll
        for (int j = 0; j < PPT; ++j) {
            uint32_t p = (uint32_t)(j * NTHREADS + tid);
            uint32_t skip = 0;
            bool isnf = false;
            for (uint32_t kk = 0; kk < nnf; ++kk) {  // nnf == 0 almost always
                uint32_t q = nonfirst[kk];
                skip += (q < p) ? 1u : 0u;
                isnf |= (q == p);
            }
            if (!isnf) {
                uint32_t key = k[j];
                float4 o;
                o.x = (float)((key >> 24) & 255u) / 127.5f - 1.0f;
                o.y = (float)((key >> 16) & 255u) / 127.5f - 1.0f;
                o.z = (float)((key >> 8)  & 255u) / 127.5f - 1.0f;
                o.w = (float)( key        & 255u) / 127.5f - 1.0f;
                dst[p - skip] = o;
            }
        }
        // ---- zero the padded tail rows (nnf rows, usually none) ----
        float4 z = make_float4(0.f, 0.f, 0.f, 0.f);
        for (uint32_t r = count + tid; r < NPIX; r += NTHREADS) dst[r] = z;
        // ---- count (written as float; whole d_out is read back as f32) ----
        if (tid == 0) out_cnt[img] = (float)count;
    }
}

extern "C" void kernel_launch(void* const* d_in, const int* in_sizes, int n_in,
                              void* d_out, int out_size, void* d_ws, size_t ws_size,
                              hipStream_t stream) {
    const float* in = (const float*)d_in[0];
    float* out = (float*)d_out;
    float* cnt = out + (size_t)BATCH * NPIX * 4;
    hipLaunchKernelGGL(palette_kernel, dim3(BATCH / IPB), dim3(NTHREADS), 0, stream,
                       in, out, cnt);
}